// Round 1
// baseline (265.767 us; speedup 1.0000x reference)
//
#include <hip/hip_runtime.h>
#include <math.h>

// Problem constants (from reference setup_inputs)
constexpr int B  = 32;
constexpr int N  = 19200;
constexpr int CH = 85;   // 4 box + 1 conf + 80 cls
constexpr float EPSF = 1e-7f;

constexpr int THREADS        = 192;            // 3 waves; 19200 % 192 == 0
constexpr int BLOCKS_PER_IMG = N / THREADS;    // 100
constexpr int GRID           = B * BLOCKS_PER_IMG;  // 3200 blocks

// ws layout (doubles): [0]=sum ciou*posf, [1]=sum cls_l*posf, [2]=sum obj,
//                      [3..34]=per-image sum posf, [35..66]=per-image sum pos_obj*posf
constexpr int WS_DOUBLES = 3 + B + B;

// BCE with logits: max(l,0) - l*t + log1p(exp(-|l|))
__device__ __forceinline__ float bce(float l, float t) {
    float sp = __logf(1.0f + __expf(-fabsf(l)));
    return fmaxf(l, 0.0f) - l * t + sp;
}

__global__ __launch_bounds__(THREADS) void loss_main(
    const float* __restrict__ outp, const float* __restrict__ tgtp,
    double* __restrict__ ws) {

    const int b      = blockIdx.x / BLOCKS_PER_IMG;          // image index (uniform per block)
    const int anchor = blockIdx.x * THREADS + threadIdx.x;   // global anchor

    const float* po = outp + (size_t)anchor * CH;
    const float* pt = tgtp + (size_t)anchor * CH;

    // ---- box + conf ----
    float pcx = po[0], pcy = po[1], pw = po[2], ph = po[3], pconf = po[4];
    float gcx = pt[0], gcy = pt[1], gw = pt[2], gh = pt[3], gconf = pt[4];

    // ---- cls: focal(alpha=0.5, gamma=0) == 0.5*ce ----
    float ce_sum = 0.0f;
    #pragma unroll 8
    for (int c = 5; c < CH; ++c) {
        ce_sum += bce(po[c], pt[c]);
    }
    float cls_l = 0.5f * ce_sum * (1.0f / 80.0f);

    // ---- CIoU (mirror reference fp32 ops) ----
    float px1 = pcx - pw * 0.5f, px2 = pcx + pw * 0.5f;
    float py1 = pcy - ph * 0.5f, py2 = pcy + ph * 0.5f;
    float gx1 = gcx - gw * 0.5f, gx2 = gcx + gw * 0.5f;
    float gy1 = gcy - gh * 0.5f, gy2 = gcy + gh * 0.5f;

    float iw    = fmaxf(fminf(px2, gx2) - fmaxf(px1, gx1), 0.0f);
    float ih    = fmaxf(fminf(py2, gy2) - fmaxf(py1, gy1), 0.0f);
    float inter = iw * ih;
    float uni   = (px2 - px1) * (py2 - py1) + (gx2 - gx1) * (gy2 - gy1) - inter;
    float iou   = inter / (uni + EPSF);

    float cw   = fmaxf(px2, gx2) - fminf(px1, gx1);
    float chh  = fmaxf(py2, gy2) - fminf(py1, gy1);
    float diag = cw * cw + chh * chh + EPSF;
    float dx   = px1 + px2 - gx1 - gx2;
    float dy   = py1 + py2 - gy1 - gy2;
    float dist = (dx * dx + dy * dy) * 0.25f;

    float w_p = px2 - px1, h_p = py2 - py1;
    float w_g = gx2 - gx1, h_g = gy2 - gy1;
    float datan = atanf(w_g / (h_g + EPSF)) - atanf(w_p / (h_p + EPSF));
    const float four_over_pi2 = 4.0f / (float)(M_PI * M_PI);
    float v = four_over_pi2 * datan * datan;
    float a = v / (1.0f - iou + v + EPSF);   // stop_gradient: forward value unchanged
    float ciou = 1.0f - iou + dist / diag + a * v;

    // ---- objectness ----
    float posf = (gconf > 0.5f) ? 1.0f : 0.0f;
    // pos: focal(l, 1, 0.5, 0)*1.5 = 0.75*ce(l,1)
    float pos_obj = 0.75f * bce(pconf, 1.0f);
    // neg: focal(l, 0, 0.5, 1.5)*0.5 = 0.25*ce(l,0)*p^1.5
    float p   = 1.0f / (1.0f + __expf(-pconf));
    float neg_obj = 0.25f * bce(pconf, 0.0f) * p * sqrtf(p);
    float obj = (posf > 0.0f) ? pos_obj : neg_obj;

    // ---- per-thread partials ----
    float v0 = ciou * posf;
    float v1 = cls_l * posf;
    float v2 = obj;
    float v3 = posf;
    float v4 = pos_obj * posf;

    // ---- wave reduce (64 lanes) ----
    #pragma unroll
    for (int off = 32; off > 0; off >>= 1) {
        v0 += __shfl_down(v0, off);
        v1 += __shfl_down(v1, off);
        v2 += __shfl_down(v2, off);
        v3 += __shfl_down(v3, off);
        v4 += __shfl_down(v4, off);
    }

    __shared__ float red[3][5];   // 3 waves per block
    const int wave = threadIdx.x >> 6;
    const int lane = threadIdx.x & 63;
    if (lane == 0) {
        red[wave][0] = v0; red[wave][1] = v1; red[wave][2] = v2;
        red[wave][3] = v3; red[wave][4] = v4;
    }
    __syncthreads();

    if (threadIdx.x == 0) {
        float s0 = red[0][0] + red[1][0] + red[2][0];
        float s1 = red[0][1] + red[1][1] + red[2][1];
        float s2 = red[0][2] + red[1][2] + red[2][2];
        float s3 = red[0][3] + red[1][3] + red[2][3];
        float s4 = red[0][4] + red[1][4] + red[2][4];
        atomicAdd(&ws[0], (double)s0);
        atomicAdd(&ws[1], (double)s1);
        atomicAdd(&ws[2], (double)s2);
        atomicAdd(&ws[3 + b],     (double)s3);
        atomicAdd(&ws[3 + B + b], (double)s4);
    }
}

__global__ void loss_final(const double* __restrict__ ws, float* __restrict__ out) {
    const int lane = threadIdx.x;
    double v = 0.0;
    if (lane < B) {
        double npos = ws[3 + lane];
        if (npos < 1.0) npos = 1.0;
        v = ws[3 + B + lane] / npos;
    }
    #pragma unroll
    for (int off = 32; off > 0; off >>= 1) v += __shfl_down(v, off);

    if (lane == 0) {
        const double inv = 1.0 / ((double)N * (double)B);
        double avg_ciou   = ws[0] * inv;
        double avg_cls    = ws[1] * inv;
        double avg_obj    = ws[2] * inv;
        double avg_posobj = v / (double)B;

        double t1 = 0.5 * avg_ciou;   // BOX_W
        double t2 = 1.5 * avg_obj;    // OBJ_W
        double t3 = 1.5 * avg_cls;    // CLS_W
        out[0] = (float)(t1 + t2 + t3);
        out[1] = (float)t1;
        out[2] = (float)t2;
        out[3] = (float)t3;
        out[4] = (float)avg_posobj;
    }
}

extern "C" void kernel_launch(void* const* d_in, const int* in_sizes, int n_in,
                              void* d_out, int out_size, void* d_ws, size_t ws_size,
                              hipStream_t stream) {
    const float* outputs = (const float*)d_in[0];
    const float* targets = (const float*)d_in[1];
    double* ws = (double*)d_ws;

    hipMemsetAsync(ws, 0, WS_DOUBLES * sizeof(double), stream);
    loss_main<<<GRID, THREADS, 0, stream>>>(outputs, targets, ws);
    loss_final<<<1, 64, 0, stream>>>(ws, (float*)d_out);
}